// Round 3
// baseline (1478.025 us; speedup 1.0000x reference)
//
#include <hip/hip_runtime.h>
#include <math.h>

#define SIZE 1024
#define BATCH 32
#define SEQ 2048
#define PARTS 16
#define EPART (SIZE / PARTS)

#define K1_BLOCKS 512          // 16 parts * 32 b * 256 d4 / 256 threads
#define K2_BLOCKS 8192         // 32768 (sp,b) wave-items / 4 waves per block

typedef float f4v __attribute__((ext_vector_type(4)));

// ---------------------------------------------------------------------------
// K1: vpart[part][b][d] = sum_{e in part} dh[b,e]*W[e,d]; then the LAST 32
// blocks to finish (by atomic ticket) reduce vpart over parts into v[b][d].
// Deterministic: reduction order is fixed, independent of ticket order.
// Spinners <= 32 << co-resident capacity -> no scheduling deadlock.
// ---------------------------------------------------------------------------
__global__ __launch_bounds__(256) void k_proj_v(const float* __restrict__ dh,
                                                const float* __restrict__ W,
                                                float* __restrict__ vpart,
                                                float* __restrict__ v,
                                                int* __restrict__ counter) {
    int tid  = blockIdx.x * 256 + threadIdx.x;      // 0 .. 131071
    int part = tid >> 13;                            // 0..15
    int rem  = tid & 8191;
    int b    = rem >> 8;                             // 0..31
    int d4   = rem & 255;                            // 0..255

    const float4* W4  = (const float4*)W;            // [SIZE][SIZE/4]
    const float*  dhb = dh + b * SIZE;
    int e0 = part * EPART;

    float4 acc = make_float4(0.f, 0.f, 0.f, 0.f);
    #pragma unroll 8
    for (int e = e0; e < e0 + EPART; ++e) {
        float  s = dhb[e];                           // wave-uniform scalar
        float4 w = W4[e * (SIZE / 4) + d4];
        acc.x += s * w.x;
        acc.y += s * w.y;
        acc.z += s * w.z;
        acc.w += s * w.w;
    }
    ((float4*)vpart)[(part * BATCH + b) * (SIZE / 4) + d4] = acc;

    // --- ticket ---
    __threadfence();
    __syncthreads();
    __shared__ int t_s;
    if (threadIdx.x == 0) t_s = atomicAdd(counter, 1);
    __syncthreads();

    if (t_s >= K1_BLOCKS - 32) {
        if (threadIdx.x == 0) {
            while (__hip_atomic_load(counter, __ATOMIC_RELAXED,
                                     __HIP_MEMORY_SCOPE_AGENT) < K1_BLOCKS)
                __builtin_amdgcn_s_sleep(1);
        }
        __syncthreads();
        __threadfence();                              // acquire: inv L1, see all vpart
        int r = t_s - (K1_BLOCKS - 32);               // 0..31
        int i = r * 256 + threadIdx.x;                // 0..8191 float4 index
        const float4* vp = (const float4*)vpart;
        float4 a = vp[i];
        #pragma unroll
        for (int p = 1; p < PARTS; ++p) {
            float4 t = vp[p * BATCH * (SIZE / 4) + i];
            a.x += t.x; a.y += t.y; a.z += t.z; a.w += t.w;
        }
        ((float4*)v)[i] = a;
    }
}

// ---------------------------------------------------------------------------
// K2: energies[b][s] = v[b] . enc[s][b][:]  (one wave per s-pair x b; enc read
// with nontemporal loads -- 268 MB streamed once, > L3, don't pollute caches).
// Then the LAST 32 ticketed blocks each run the softmax for one batch row.
// Bias term is constant over s and cancels under softmax shift invariance.
// ---------------------------------------------------------------------------
__global__ __launch_bounds__(256) void k_energy_softmax(const float* __restrict__ enc,
                                                        const float* __restrict__ v,
                                                        float* __restrict__ energies,
                                                        float* __restrict__ out,
                                                        int* __restrict__ counter) {
    int wave = blockIdx.x * 4 + (threadIdx.x >> 6);  // 0..32767
    int lane = threadIdx.x & 63;
    int b  = wave & 31;                              // 0..31
    int sp = wave >> 5;                              // 0..1023 (s-pair)
    size_t s0 = (size_t)sp * 2;

    const f4v* row0 = (const f4v*)(enc + (s0 * BATCH + b) * SIZE);
    const f4v* row1 = (const f4v*)(enc + ((s0 + 1) * BATCH + b) * SIZE);
    const f4v* vb   = (const f4v*)(v + b * SIZE);

    float a0 = 0.f, a1 = 0.f;
    #pragma unroll
    for (int k = 0; k < 4; ++k) {
        f4v e0 = __builtin_nontemporal_load(row0 + lane + (k << 6));
        f4v e1 = __builtin_nontemporal_load(row1 + lane + (k << 6));
        f4v vv = vb[lane + (k << 6)];
        a0 += e0.x * vv.x + e0.y * vv.y + e0.z * vv.z + e0.w * vv.w;
        a1 += e1.x * vv.x + e1.y * vv.y + e1.z * vv.z + e1.w * vv.w;
    }
    #pragma unroll
    for (int off = 32; off; off >>= 1) {
        a0 += __shfl_down(a0, off, 64);
        a1 += __shfl_down(a1, off, 64);
    }
    if (lane == 0)
        ((float2*)(energies + b * SEQ))[sp] = make_float2(a0, a1);

    // --- ticket ---
    __threadfence();
    __syncthreads();
    __shared__ int t_s;
    if (threadIdx.x == 0) t_s = atomicAdd(counter, 1);
    __syncthreads();

    if (t_s >= K2_BLOCKS - 32) {
        if (threadIdx.x == 0) {
            while (__hip_atomic_load(counter, __ATOMIC_RELAXED,
                                     __HIP_MEMORY_SCOPE_AGENT) < K2_BLOCKS)
                __builtin_amdgcn_s_sleep(1);
        }
        __syncthreads();
        __threadfence();                              // acquire: see all energies

        int brow = t_s - (K2_BLOCKS - 32);            // 0..31
        const float* row = energies + brow * SEQ;
        int t = threadIdx.x;
        int wid = t >> 6, ln = t & 63;

        float vals[8];
        float m = -INFINITY;
        #pragma unroll
        for (int i = 0; i < 8; ++i) {
            vals[i] = row[t + (i << 8)];
            m = fmaxf(m, vals[i]);
        }
        __shared__ float redm[4];
        #pragma unroll
        for (int off = 32; off; off >>= 1) m = fmaxf(m, __shfl_down(m, off, 64));
        if (ln == 0) redm[wid] = m;
        __syncthreads();
        m = fmaxf(fmaxf(redm[0], redm[1]), fmaxf(redm[2], redm[3]));

        float sum = 0.f;
        #pragma unroll
        for (int i = 0; i < 8; ++i) {
            vals[i] = __expf(vals[i] - m);
            sum += vals[i];
        }
        __shared__ float reds[4];
        #pragma unroll
        for (int off = 32; off; off >>= 1) sum += __shfl_down(sum, off, 64);
        if (ln == 0) reds[wid] = sum;
        __syncthreads();
        sum = reds[0] + reds[1] + reds[2] + reds[3];

        float inv = 1.f / sum;
        #pragma unroll
        for (int i = 0; i < 8; ++i)
            out[brow * SEQ + t + (i << 8)] = vals[i] * inv;
    }
}

// ---------------------------------------------------------------------------
extern "C" void kernel_launch(void* const* d_in, const int* in_sizes, int n_in,
                              void* d_out, int out_size, void* d_ws, size_t ws_size,
                              hipStream_t stream) {
    const float* dh  = (const float*)d_in[0];   // [32, 1024]
    const float* enc = (const float*)d_in[1];   // [2048, 32, 1024]
    const float* W   = (const float*)d_in[2];   // [1024, 1024]
    // d_in[3] = bias: unused (cancels under softmax shift invariance)

    float* ws       = (float*)d_ws;
    float* vpart    = ws;                                   // 16*32*1024 = 131072 f
    float* v        = vpart + PARTS * BATCH * SIZE;         // 32*1024    =  32768 f
    float* energies = v + BATCH * SIZE;                     // 32*2048    =  65536 f
    int*   counters = (int*)(energies + BATCH * SEQ);       // 2 ints

    hipMemsetAsync(counters, 0, 2 * sizeof(int), stream);

    k_proj_v<<<K1_BLOCKS, 256, 0, stream>>>(dh, W, vpart, v, counters + 0);
    k_energy_softmax<<<K2_BLOCKS, 256, 0, stream>>>(enc, v, energies,
                                                    (float*)d_out, counters + 1);
}

// Round 4
// 61.904 us; speedup vs baseline: 23.8762x; 23.8762x over previous
//
#include <hip/hip_runtime.h>
#include <math.h>

#define SIZE 1024
#define BATCH 32
#define SEQ 2048
#define PARTS 16         // e-dim split for k_project parallelism (2048 waves)
#define EPART (SIZE / PARTS)

// ---------------------------------------------------------------------------
// Kernel 1: partial projection  vpart[part][b][d] = sum_{e in part} dh[b,e]*W[e,d]
// 131072 threads = 512 blocks x 256 -> plenty of TLP to hide L2 latency on the
// W stream (W is 4MB, L2-resident after first touch).
// ---------------------------------------------------------------------------
__global__ __launch_bounds__(256) void k_project(const float* __restrict__ dh,
                                                 const float* __restrict__ W,
                                                 float* __restrict__ vpart) {
    int tid  = blockIdx.x * 256 + threadIdx.x;      // 0 .. 131071
    int part = tid >> 13;                            // 0..15
    int rem  = tid & 8191;
    int b    = rem >> 8;                             // 0..31
    int d4   = rem & 255;                            // 0..255 (float4 granule)

    const float4* W4  = (const float4*)W;            // [SIZE][SIZE/4]
    const float*  dhb = dh + b * SIZE;
    int e0 = part * EPART;

    float4 acc = make_float4(0.f, 0.f, 0.f, 0.f);
    #pragma unroll 8
    for (int e = e0; e < e0 + EPART; ++e) {
        float  s = dhb[e];                           // wave-uniform scalar
        float4 w = W4[e * (SIZE / 4) + d4];
        acc.x += s * w.x;
        acc.y += s * w.y;
        acc.z += s * w.z;
        acc.w += s * w.w;
    }
    ((float4*)vpart)[(part * BATCH + b) * (SIZE / 4) + d4] = acc;
}

// ---------------------------------------------------------------------------
// Kernel 2: v[b][d] = sum over 16 parts of vpart. 8192 float4 elems, 32 blocks.
// ---------------------------------------------------------------------------
__global__ __launch_bounds__(256) void k_reduce(const float* __restrict__ vpart,
                                                float* __restrict__ v) {
    int i = blockIdx.x * 256 + threadIdx.x;          // 0 .. 8191 (float4 index)
    const float4* vp = (const float4*)vpart;
    float4 a = vp[i];
    #pragma unroll
    for (int p = 1; p < PARTS; ++p) {
        float4 t = vp[p * BATCH * (SIZE / 4) + i];
        a.x += t.x; a.y += t.y; a.z += t.z; a.w += t.w;
    }
    ((float4*)v)[i] = a;
}

// ---------------------------------------------------------------------------
// Kernel 3: energies[b][s] = v[b] . enc[s][b][:]
// One wave per (s-quad, b): four adjacent s rows share the v operand and give
// 16 independent 1KB enc loads in flight per wave. 16384 waves = 4096 blocks.
// This kernel carries the 268 MB HBM read. Plain (cached) loads -- the nt
// variant regressed 25x in round 3.
// ---------------------------------------------------------------------------
__global__ __launch_bounds__(256) void k_energies(const float* __restrict__ enc,
                                                  const float* __restrict__ v,
                                                  float* __restrict__ energies) {
    int wave = blockIdx.x * 4 + (threadIdx.x >> 6);  // 0..16383
    int lane = threadIdx.x & 63;
    int b  = wave & 31;                              // 0..31
    int sq = wave >> 5;                              // 0..511 (s-quad)
    size_t s0 = (size_t)sq * 4;

    const float4* row0 = (const float4*)(enc + ((s0 + 0) * BATCH + b) * SIZE);
    const float4* row1 = (const float4*)(enc + ((s0 + 1) * BATCH + b) * SIZE);
    const float4* row2 = (const float4*)(enc + ((s0 + 2) * BATCH + b) * SIZE);
    const float4* row3 = (const float4*)(enc + ((s0 + 3) * BATCH + b) * SIZE);
    const float4* vb   = (const float4*)(v + b * SIZE);

    float a0 = 0.f, a1 = 0.f, a2 = 0.f, a3 = 0.f;
    #pragma unroll
    for (int k = 0; k < 4; ++k) {
        int idx = lane + (k << 6);
        float4 e0 = row0[idx];
        float4 e1 = row1[idx];
        float4 e2 = row2[idx];
        float4 e3 = row3[idx];
        float4 vv = vb[idx];
        a0 += e0.x * vv.x + e0.y * vv.y + e0.z * vv.z + e0.w * vv.w;
        a1 += e1.x * vv.x + e1.y * vv.y + e1.z * vv.z + e1.w * vv.w;
        a2 += e2.x * vv.x + e2.y * vv.y + e2.z * vv.z + e2.w * vv.w;
        a3 += e3.x * vv.x + e3.y * vv.y + e3.z * vv.z + e3.w * vv.w;
    }
    #pragma unroll
    for (int off = 32; off; off >>= 1) {
        a0 += __shfl_down(a0, off, 64);
        a1 += __shfl_down(a1, off, 64);
        a2 += __shfl_down(a2, off, 64);
        a3 += __shfl_down(a3, off, 64);
    }
    if (lane == 0)
        ((float4*)(energies + b * SEQ))[sq] = make_float4(a0, a1, a2, a3);
}

// ---------------------------------------------------------------------------
// Kernel 4: row softmax over s. One block per b; 256 threads x 8 elems each,
// values kept in registers across the max/exp/sum passes.
// Note: the reference's "+ dh[b].bias" term is constant over s and cancels in
// softmax (shift invariance) -- bias input is intentionally unused.
// ---------------------------------------------------------------------------
__global__ __launch_bounds__(256) void k_softmax(const float* __restrict__ energies,
                                                 float* __restrict__ out) {
    int b = blockIdx.x;
    const float* row = energies + b * SEQ;
    int t = threadIdx.x;
    int wid = t >> 6, lane = t & 63;

    float vals[8];
    float m = -INFINITY;
    #pragma unroll
    for (int i = 0; i < 8; ++i) {
        vals[i] = row[t + (i << 8)];
        m = fmaxf(m, vals[i]);
    }
    __shared__ float redm[4];
    #pragma unroll
    for (int off = 32; off; off >>= 1) m = fmaxf(m, __shfl_down(m, off, 64));
    if (lane == 0) redm[wid] = m;
    __syncthreads();
    m = fmaxf(fmaxf(redm[0], redm[1]), fmaxf(redm[2], redm[3]));

    float sum = 0.f;
    #pragma unroll
    for (int i = 0; i < 8; ++i) {
        vals[i] = __expf(vals[i] - m);
        sum += vals[i];
    }
    __shared__ float reds[4];
    #pragma unroll
    for (int off = 32; off; off >>= 1) sum += __shfl_down(sum, off, 64);
    if (lane == 0) reds[wid] = sum;
    __syncthreads();
    sum = reds[0] + reds[1] + reds[2] + reds[3];

    float inv = 1.f / sum;
    #pragma unroll
    for (int i = 0; i < 8; ++i)
        out[b * SEQ + t + (i << 8)] = vals[i] * inv;
}

// ---------------------------------------------------------------------------
extern "C" void kernel_launch(void* const* d_in, const int* in_sizes, int n_in,
                              void* d_out, int out_size, void* d_ws, size_t ws_size,
                              hipStream_t stream) {
    const float* dh  = (const float*)d_in[0];   // [32, 1024]
    const float* enc = (const float*)d_in[1];   // [2048, 32, 1024]
    const float* W   = (const float*)d_in[2];   // [1024, 1024]
    // d_in[3] = bias: unused (cancels under softmax shift invariance)

    float* ws       = (float*)d_ws;
    float* vpart    = ws;                                   // 16*32*1024 = 524288 f
    float* v        = vpart + PARTS * BATCH * SIZE;         // 32*1024    =  32768 f
    float* energies = v + BATCH * SIZE;                     // 32*2048    =  65536 f

    k_project <<<PARTS * BATCH * (SIZE / 4) / 256, 256, 0, stream>>>(dh, W, vpart);
    k_reduce  <<<BATCH * (SIZE / 4) / 256, 256, 0, stream>>>(vpart, v);
    k_energies<<<(BATCH * SEQ / 4) / 4, 256, 0, stream>>>(enc, v, energies);
    k_softmax <<<BATCH, 256, 0, stream>>>(energies, (float*)d_out);
}